// Round 1
// baseline (275.238 us; speedup 1.0000x reference)
//
#include <hip/hip_runtime.h>

#define NCAM 4
#define C 336
#define H 96
#define W 176
#define D 6
#define HB 240
#define WB 120
#define HW (H * W)            // 16896
#define CC 64                 // c-chunk (lane dim)
#define WPW (WB / 4)          // 30 wb per wave

// ---------------------------------------------------------------------------
// Pass 1: transpose feat[cam][c][h*w] -> tfeat[cam][h*w][c]
// so that per-(v,u) channel columns become contiguous (coalesced gathers).
// ---------------------------------------------------------------------------
__global__ __launch_bounds__(256)
void vp_transpose_kernel(const float* __restrict__ in, float* __restrict__ out) {
    __shared__ float tile[32][33];
    const int cam = blockIdx.z;
    const int hw0 = blockIdx.x * 32;   // HW = 528 * 32 exact
    const int c0  = blockIdx.y * 32;   // C = 336 -> last tile partial (16 rows)
    const int tx = threadIdx.x;        // 0..31
    const int ty = threadIdx.y;        // 0..7

    const float* src = in + (size_t)cam * C * HW;
#pragma unroll
    for (int k = 0; k < 32; k += 8) {
        int c = c0 + ty + k;
        if (c < C) tile[ty + k][tx] = src[(size_t)c * HW + (hw0 + tx)];
    }
    __syncthreads();
    float* dst = out + (size_t)cam * HW * C;
#pragma unroll
    for (int k = 0; k < 32; k += 8) {
        int c = c0 + tx;
        int hw = hw0 + ty + k;
        if (c < C) dst[(size_t)hw * C + c] = tile[tx][ty + k];
    }
}

// ---------------------------------------------------------------------------
// Pass 2: one block per (d, hb). Stage per-(cam,wb) gather offset + weight in
// LDS, then loop c in chunks of CC (lane = c offset). Each wave owns 30 wb
// columns, accumulates the 4-camera weighted sum in registers (coalesced
// loads along c in transposed layout), transposes the CC x WB tile through
// LDS, and stores coalesced along wb.
// cstride = 1 for transposed feat; = HW for original layout (fallback).
// ---------------------------------------------------------------------------
__global__ __launch_bounds__(256)
void vp_gather_kernel(const float* __restrict__ feat, const int cstride,
                      const int* __restrict__ pu, const int* __restrict__ pv,
                      const int* __restrict__ pvalid,
                      const float* __restrict__ pdens,
                      float* __restrict__ out) {
    __shared__ int   s_off[NCAM][WB];
    __shared__ float s_wgt[NCAM][WB];
    __shared__ float s_acc[CC][WB + 1];

    const int d   = blockIdx.x / HB;
    const int hb  = blockIdx.x % HB;
    const int tid = threadIdx.x;

    // Stage projection data: 4 cams x 120 wb
    for (int i = tid; i < NCAM * WB; i += 256) {
        int cam = i / WB, wb = i % WB;
        size_t pidx = ((size_t)(cam * D + d) * HB + hb) * WB + wb;
        int u = pu[pidx];
        int v = pv[pidx];
        float w = pvalid[pidx] ? pdens[pidx] : 0.0f;
        int off;
        if (cstride == 1) {
            off = cam * (HW * C) + (v * W + u) * C;   // transposed layout
        } else {
            off = cam * (C * HW) + v * W + u;         // original layout
        }
        s_off[cam][wb] = off;
        s_wgt[cam][wb] = w;
    }
    __syncthreads();

    const int wave = tid >> 6;   // 0..3
    const int lane = tid & 63;   // = c offset within chunk

    for (int c0 = 0; c0 < C; c0 += CC) {
        const int c = c0 + lane;
        const bool cvalid = (c < C);

        float acc[WPW];
#pragma unroll
        for (int wbi = 0; wbi < WPW; ++wbi) {
            const int wb = wave * WPW + wbi;
            float a = 0.0f;
            if (cvalid) {
#pragma unroll
                for (int cam = 0; cam < NCAM; ++cam) {
                    a += s_wgt[cam][wb] *
                         feat[(size_t)s_off[cam][wb] + (size_t)c * cstride];
                }
            }
            acc[wbi] = a;
        }

        // register tile -> LDS (row = c-lane, col = wb); stride 121 words
#pragma unroll
        for (int wbi = 0; wbi < WPW; ++wbi) {
            const int wb = wave * WPW + wbi;
            s_acc[lane][wb] = acc[wbi];
        }
        __syncthreads();

        // coalesced store: lanes sweep wb
        const int wb2 = tid & 127;
        const int r0  = tid >> 7;   // 0 or 1
        if (wb2 < WB) {
            for (int r = r0; r < CC; r += 2) {
                const int cc = c0 + r;
                if (cc < C)
                    out[(((size_t)d * C + cc) * HB + hb) * WB + wb2] =
                        s_acc[r][wb2];
            }
        }
        __syncthreads();
    }
}

extern "C" void kernel_launch(void* const* d_in, const int* in_sizes, int n_in,
                              void* d_out, int out_size, void* d_ws,
                              size_t ws_size, hipStream_t stream) {
    const float* feat  = (const float*)d_in[0];
    const int* pu      = (const int*)d_in[1];
    const int* pv      = (const int*)d_in[2];
    const int* pvalid  = (const int*)d_in[3];
    const float* pdens = (const float*)d_in[4];
    float* out         = (float*)d_out;

    const size_t tfeat_bytes = (size_t)NCAM * HW * C * sizeof(float);

    if (ws_size >= tfeat_bytes) {
        float* tfeat = (float*)d_ws;
        dim3 tgrid(HW / 32, (C + 31) / 32, NCAM);
        dim3 tblock(32, 8);
        vp_transpose_kernel<<<tgrid, tblock, 0, stream>>>(feat, tfeat);
        vp_gather_kernel<<<D * HB, 256, 0, stream>>>(tfeat, 1, pu, pv, pvalid,
                                                     pdens, out);
    } else {
        // Fallback: gather directly from original layout (uncoalesced, slow
        // but correct) if workspace is too small for the transposed copy.
        vp_gather_kernel<<<D * HB, 256, 0, stream>>>(feat, HW, pu, pv, pvalid,
                                                     pdens, out);
    }
}

// Round 2
// 179.038 us; speedup vs baseline: 1.5373x; 1.5373x over previous
//
#include <hip/hip_runtime.h>

#define NCAM 4
#define C 336
#define H 96
#define W 176
#define D 6
#define HB 240
#define WB 120
#define HW (H * W)        // 16896
#define CPB 112           // channels per block (3 c-parts * 112 = 336)
#define NPARTS 3
#define HALFROWS 56       // c-rows dumped to LDS per store phase

static __device__ __forceinline__ unsigned short f2bf(float f) {
    unsigned u = __float_as_uint(f);
    unsigned r = (u + 0x7fffu + ((u >> 16) & 1u)) >> 16;   // RNE
    return (unsigned short)r;
}

// ---------------------------------------------------------------------------
// Pass 1: feat[cam][c][h*w] (f32) -> tfeat[cam][h*w][c] (bf16)
// ---------------------------------------------------------------------------
__global__ __launch_bounds__(256)
void vp_transpose_bf16(const float* __restrict__ in,
                       unsigned short* __restrict__ out) {
    __shared__ float tile[32][33];
    const int cam = blockIdx.z;
    const int hw0 = blockIdx.x * 32;     // HW = 528*32 exact
    const int c0  = blockIdx.y * 32;     // 11 tiles, last partial (16)
    const int tx = threadIdx.x;          // 0..31
    const int ty = threadIdx.y;          // 0..7

    const float* src = in + (size_t)cam * C * HW;
#pragma unroll
    for (int k = 0; k < 32; k += 8) {
        int c = c0 + ty + k;
        if (c < C) tile[ty + k][tx] = src[(size_t)c * HW + (hw0 + tx)];
    }
    __syncthreads();

    unsigned* dst = (unsigned*)(out + (size_t)cam * HW * C);
    const int tid = ty * 32 + tx;
    const int cp     = tid & 15;         // c-pair index within tile
    const int hwbase = tid >> 4;         // 0..15
    const int c = c0 + cp * 2;
    if (c < C) {
#pragma unroll
        for (int k = 0; k < 2; ++k) {
            int hwl = hwbase + k * 16;
            unsigned ulo = f2bf(tile[cp * 2][hwl]);
            unsigned uhi = f2bf(tile[cp * 2 + 1][hwl]);
            dst[((size_t)(hw0 + hwl) * C + c) >> 1] = ulo | (uhi << 16);
        }
    }
}

// ---------------------------------------------------------------------------
// Pass 2: one block per (d, hb, c-part of 112 channels).
// Lane map: cq = lane>>2 (14 active, 8 channels each via one uint4 = 8 bf16),
// wbsub = lane&3; wave owns 30 wb (wb = wave*30 + wbsub + 4*wbi).
// acc[8][8] f32 in registers; two LDS dump+store phases of 56 c-rows each.
// ---------------------------------------------------------------------------
__global__ __launch_bounds__(256, 4)
void vp_gather_bf16(const unsigned short* __restrict__ tfeat,
                    const int* __restrict__ pu, const int* __restrict__ pv,
                    const int* __restrict__ pvalid,
                    const float* __restrict__ pdens,
                    float* __restrict__ out) {
    __shared__ int   s_off[NCAM][WB];
    __shared__ float s_wgt[NCAM][WB];
    __shared__ float s_acc[HALFROWS][121];

    const int d     = blockIdx.x / HB;
    const int hb    = blockIdx.x % HB;
    const int cpart = blockIdx.y;
    const int tid   = threadIdx.x;

    for (int i = tid; i < NCAM * WB; i += 256) {
        int cam = i / WB, wb = i % WB;
        size_t pidx = ((size_t)(cam * D + d) * HB + hb) * WB + wb;
        float w = pvalid[pidx] ? pdens[pidx] : 0.0f;
        s_off[cam][wb] = cam * (HW * C) + (pv[pidx] * W + pu[pidx]) * C;
        s_wgt[cam][wb] = w;
    }
    __syncthreads();

    const int wave  = tid >> 6;
    const int lane  = tid & 63;
    const int cq    = lane >> 2;         // 0..15, active < 14
    const int wbsub = lane & 3;
    const bool cact = (cq < 14);
    const int cbase = cpart * CPB + cq * 8;

    float acc[8][8];
#pragma unroll
    for (int i = 0; i < 8; ++i)
#pragma unroll
        for (int j = 0; j < 8; ++j) acc[i][j] = 0.0f;

#pragma unroll
    for (int wbi = 0; wbi < 8; ++wbi) {
        const int wbl = wbsub + 4 * wbi;          // 0..31, active < 30
        const int wb  = wave * 30 + (wbl < 30 ? wbl : 29);
        const bool act = cact && (wbl < 30);
#pragma unroll
        for (int cam = 0; cam < NCAM; ++cam) {
            if (act) {
                const uint4 q = *(const uint4*)(tfeat + (size_t)s_off[cam][wb] + cbase);
                const float w = s_wgt[cam][wb];
                acc[wbi][0] += w * __uint_as_float(q.x << 16);
                acc[wbi][1] += w * __uint_as_float(q.x & 0xffff0000u);
                acc[wbi][2] += w * __uint_as_float(q.y << 16);
                acc[wbi][3] += w * __uint_as_float(q.y & 0xffff0000u);
                acc[wbi][4] += w * __uint_as_float(q.z << 16);
                acc[wbi][5] += w * __uint_as_float(q.z & 0xffff0000u);
                acc[wbi][6] += w * __uint_as_float(q.w << 16);
                acc[wbi][7] += w * __uint_as_float(q.w & 0xffff0000u);
            }
        }
    }

    for (int half = 0; half < 2; ++half) {
        // dump: lanes with cq in [half*7, half*7+7) own rows (cq-half*7)*8+j
        if (cact && cq >= half * 7 && cq < half * 7 + 7) {
            const int rbase = (cq - half * 7) * 8;
#pragma unroll
            for (int wbi = 0; wbi < 8; ++wbi) {
                const int wbl = wbsub + 4 * wbi;
                if (wbl < 30) {
#pragma unroll
                    for (int j = 0; j < 8; ++j)
                        s_acc[rbase + j][wave * 30 + wbl] = acc[wbi][j];
                }
            }
        }
        __syncthreads();

        // store: 56 rows x 120 wb, coalesced float4 along wb
        const int wb4 = tid & 31;        // active < 30
        const int rb  = tid >> 5;        // 0..7
        if (wb4 < 30) {
#pragma unroll
            for (int k = 0; k < 7; ++k) {
                const int r = rb + 8 * k;
                const int c = cpart * CPB + half * HALFROWS + r;
                float4 v;
                v.x = s_acc[r][wb4 * 4 + 0];
                v.y = s_acc[r][wb4 * 4 + 1];
                v.z = s_acc[r][wb4 * 4 + 2];
                v.w = s_acc[r][wb4 * 4 + 3];
                *(float4*)(out + (((size_t)d * C + c) * HB + hb) * WB + wb4 * 4) = v;
            }
        }
        __syncthreads();
    }
}

extern "C" void kernel_launch(void* const* d_in, const int* in_sizes, int n_in,
                              void* d_out, int out_size, void* d_ws,
                              size_t ws_size, hipStream_t stream) {
    const float* feat  = (const float*)d_in[0];
    const int* pu      = (const int*)d_in[1];
    const int* pv      = (const int*)d_in[2];
    const int* pvalid  = (const int*)d_in[3];
    const float* pdens = (const float*)d_in[4];
    float* out         = (float*)d_out;

    unsigned short* tfeat = (unsigned short*)d_ws;   // 45.4 MB, ws proven >=86 MB

    dim3 tgrid(HW / 32, (C + 31) / 32, NCAM);
    dim3 tblock(32, 8);
    vp_transpose_bf16<<<tgrid, tblock, 0, stream>>>(feat, tfeat);

    dim3 ggrid(D * HB, NPARTS);
    vp_gather_bf16<<<ggrid, 256, 0, stream>>>(tfeat, pu, pv, pvalid, pdens, out);
}